// Round 4
// baseline (336.421 us; speedup 1.0000x reference)
//
#include <hip/hip_runtime.h>

#define COLS 2048
#define KSEL 256
#define TPB  256
#define RPB  4            // rows per block = waves per block
#define LPT  32           // elements per lane (one wave per row)
#define RSTRIDE 1088      // LDS words per row region (16B-aligned stride)
// Per-row region layout (word offsets):
//   [0..1055]   P1 hist [4][264] replica-major; rep0[0..255] reused by later passes
//   [264..519]  compact buffer (cap 256)  -- valid after P1 hist consumed
//   [528..591]  recompact buffer (cap 64)
//   [792..855]  trash (64 words, garbage sink for branchless stores/atomics)
#define BUFOFF   264
#define R2OFF    528
#define TRASHOFF 792

__device__ __forceinline__ unsigned mbcnt64(unsigned long long m) {
    unsigned c = __builtin_amdgcn_mbcnt_lo((unsigned)m, 0u);
    return __builtin_amdgcn_mbcnt_hi((unsigned)(m >> 32), c);
}
__device__ __forceinline__ unsigned rfl(unsigned v) {
    return (unsigned)__builtin_amdgcn_readfirstlane((int)v);
}

// One WAVE per row; no __syncthreads anywhere (wave-private LDS regions).
// Exact top-K radix select on score bits (non-negative floats -> uint monotone).
// Tie handling matches jax.lax.top_k (lower column index first).
__global__ __launch_bounds__(TPB, 8)
void CompetitiveSelection_topk_kernel(const float* __restrict__ x,
                                      const float* __restrict__ imp,
                                      float* __restrict__ out)
{
    __shared__ __align__(16) unsigned int lds[RPB * RSTRIDE];
    const int lane = threadIdx.x & 63;
    const int wid  = threadIdx.x >> 6;
    unsigned int* reg = lds + wid * RSTRIDE;
    const int row = blockIdx.x * RPB + wid;
    const long gb = (long)row * COLS + lane * LPT;
    const float* xr = x + gb;
    const float* ir = imp + lane * LPT;

    // ---- load + score (xv not kept: x re-read in epilogue, L3-hot) ----
    unsigned int sc[LPT];
#pragma unroll
    for (int c = 0; c < 4; ++c) {
        float4 xa = *(const float4*)(xr + 8 * c);
        float4 xb = *(const float4*)(xr + 8 * c + 4);
        float4 ia = *(const float4*)(ir + 8 * c);
        float4 ib = *(const float4*)(ir + 8 * c + 4);
        sc[8*c+0] = __float_as_uint(fabsf(xa.x) * fabsf(ia.x));
        sc[8*c+1] = __float_as_uint(fabsf(xa.y) * fabsf(ia.y));
        sc[8*c+2] = __float_as_uint(fabsf(xa.z) * fabsf(ia.z));
        sc[8*c+3] = __float_as_uint(fabsf(xa.w) * fabsf(ia.w));
        sc[8*c+4] = __float_as_uint(fabsf(xb.x) * fabsf(ib.x));
        sc[8*c+5] = __float_as_uint(fabsf(xb.y) * fabsf(ib.y));
        sc[8*c+6] = __float_as_uint(fabsf(xb.z) * fabsf(ib.z));
        sc[8*c+7] = __float_as_uint(fabsf(xb.w) * fabsf(ib.w));
    }

    unsigned T = 0, kk = KSEL, na = 0, hm = 0xFF800000u;
    int nb = 23;

    // in-wave: suffix-scan 256 bin counts (4/lane), find crossing bin, broadcast
    auto scanfind = [&](const unsigned* c4, unsigned curT, int shift, unsigned curkk) {
        unsigned tot = c4[0] + c4[1] + c4[2] + c4[3];
        unsigned S = tot;
#pragma unroll
        for (int off = 1; off < 64; off <<= 1) {
            unsigned u = __shfl_down(S, off);
            if (lane + off < 64) S += u;
        }
        unsigned above = S - tot;          // count in bins > 4*lane+3
        int cc = -1; unsigned cab = 0, cnb = 0;
#pragma unroll
        for (int b = 3; b >= 0; --b) {
            if (cc < 0 && above < curkk && above + c4[b] >= curkk) {
                cc = 4 * lane + b; cab = above; cnb = c4[b];
            }
            above += c4[b];
        }
        unsigned long long m = __ballot(cc >= 0);   // exactly one lane
        int src = __ffsll(m) - 1;
        T  = rfl(curT | ((unsigned)__shfl(cc, src) << shift));
        kk = rfl(curkk - (unsigned)__shfl((int)cab, src));
        na = rfl((unsigned)__shfl((int)cnb, src));
    };

    // =================== P1: bits[30:23], 4 salted replicas ===================
    {
#pragma unroll
        for (int k = 0; k < 4; ++k)
            *(uint4*)&reg[256 * k + 4 * lane] = make_uint4(0, 0, 0, 0);
        reg[1024 + (lane & 31)] = 0;       // words 1024..1055 (dup writes benign)

        const unsigned rb = 264u * (lane & 3u);
#pragma unroll
        for (int j = 0; j < LPT; ++j)
            atomicAdd(&reg[rb + (sc[j] >> 23)], 1u);

        unsigned c4[4];
        uint4 a = *(const uint4*)&reg[0 * 264 + 4 * lane];
        uint4 b = *(const uint4*)&reg[1 * 264 + 4 * lane];
        uint4 c = *(const uint4*)&reg[2 * 264 + 4 * lane];
        uint4 d = *(const uint4*)&reg[3 * 264 + 4 * lane];
        c4[0] = a.x + b.x + c.x + d.x;
        c4[1] = a.y + b.y + c.y + d.y;
        c4[2] = a.z + b.z + c.z + d.z;
        c4[3] = a.w + b.w + c.w + d.w;
        scanfind(c4, 0u, 23, KSEL);
    }

    unsigned nlist = 0; bool haveList = false;

    // compact active values (<=256) from regs into BUF (positions not needed)
    auto compact = [&]() {
        unsigned run = 0;
#pragma unroll
        for (int j = 0; j < LPT; ++j) {
            bool act = (sc[j] & hm) == T;
            unsigned long long m = __ballot(act);
            unsigned pos = run + mbcnt64(m);
            unsigned addr = act ? (BUFOFF + pos) : (TRASHOFF + (unsigned)lane);
            reg[addr] = sc[j];
            run += (unsigned)__popcll(m);
        }
        nlist = rfl(run);
        haveList = true;
    };

    // histogram pass over compacted list (<=4 slots/lane), digit bits[s+7:s]
    auto listpass = [&](int s) {
        *(uint4*)&reg[4 * lane] = make_uint4(0, 0, 0, 0);
        const int nk = ((int)nlist + 63) >> 6;
        for (int k = 0; k < nk; ++k) {
            unsigned idx = (unsigned)lane + 64u * k;
            unsigned v = reg[BUFOFF + (idx & 255u)];
            bool act = (idx < nlist) && ((v & hm) == T);
            unsigned addr = act ? ((v >> s) & 255u) : (TRASHOFF + (unsigned)lane);
            atomicAdd(&reg[addr], 1u);
        }
        unsigned c4[4];
        uint4 h = *(const uint4*)&reg[4 * lane];
        c4[0] = h.x; c4[1] = h.y; c4[2] = h.z; c4[3] = h.w;
        scanfind(c4, T, s, kk);
    };

    // fallback: histogram pass over all 32 regs (rows with fat boundary bins)
    auto fullpass = [&](int s) {
        *(uint4*)&reg[4 * lane] = make_uint4(0, 0, 0, 0);
#pragma unroll
        for (int j = 0; j < LPT; ++j) {
            bool act = (sc[j] & hm) == T;
            unsigned addr = act ? ((sc[j] >> s) & 255u) : (TRASHOFF + (unsigned)lane);
            atomicAdd(&reg[addr], 1u);
        }
        unsigned c4[4];
        uint4 h = *(const uint4*)&reg[4 * lane];
        c4[0] = h.x; c4[1] = h.y; c4[2] = h.z; c4[3] = h.w;
        scanfind(c4, T, s, kk);
    };

    while (na > 64u && nb > 0) {
        int s = (nb == 23) ? 15 : (nb == 15) ? 7 : 0;
        if (!haveList && na <= 256u) compact();
        if (haveList) listpass(s); else fullpass(s);
        nb = s; hm |= (0xFFu << s);
    }

    unsigned ne;
    if (na > 64u) {
        ne = na;                            // nb==0: crossing count == #equals
    } else {
        if (!haveList) compact();           // na<=64<=256, capacity fine
        if (nb > 0) {
            // recompact currently-active list entries into R2 (<=64)
            unsigned run2 = 0;
            const int nk = ((int)nlist + 63) >> 6;
            for (int k = 0; k < nk; ++k) {
                unsigned idx = (unsigned)lane + 64u * k;
                unsigned v = reg[BUFOFF + (idx & 255u)];
                bool act = (idx < nlist) && ((v & hm) == T);
                unsigned long long m = __ballot(act);
                unsigned pos = run2 + mbcnt64(m);
                unsigned addr = act ? (R2OFF + pos) : (TRASHOFF + (unsigned)lane);
                reg[addr] = v;
                run2 += (unsigned)__popcll(m);
            }
            unsigned na2 = rfl(run2);       // == na
            // wave ballot-radix over remaining nb bits (exact)
            unsigned v = reg[R2OFF + lane];
            unsigned long long M = __ballot((unsigned)lane < na2);
            unsigned tl = 0, k2 = kk;
            for (int b = nb - 1; b >= 0; --b) {
                unsigned long long ones = __ballot((v >> b) & 1u) & M;
                unsigned c1 = (unsigned)__popcll(ones);
                if (c1 >= k2) { M = ones; tl |= (1u << b); }
                else          { M &= ~ones; k2 -= c1; }
            }
            T = rfl(T | tl); kk = rfl(k2); ne = rfl((unsigned)__popcll(M));
        } else {
            ne = na;
        }
    }

    // ---- epilogue: re-read x (L3-hot), apply exact mask ----
    float* orow = out + gb;
    if (ne == kk) {                         // no boundary-tie split (common)
#pragma unroll
        for (int c = 0; c < 4; ++c) {
            float4 xa = *(const float4*)(xr + 8 * c);
            float4 xb = *(const float4*)(xr + 8 * c + 4);
            float4 oa, ob;
            oa.x = (sc[8*c+0] >= T) ? xa.x : 0.0f;
            oa.y = (sc[8*c+1] >= T) ? xa.y : 0.0f;
            oa.z = (sc[8*c+2] >= T) ? xa.z : 0.0f;
            oa.w = (sc[8*c+3] >= T) ? xa.w : 0.0f;
            ob.x = (sc[8*c+4] >= T) ? xb.x : 0.0f;
            ob.y = (sc[8*c+5] >= T) ? xb.y : 0.0f;
            ob.z = (sc[8*c+6] >= T) ? xb.z : 0.0f;
            ob.w = (sc[8*c+7] >= T) ? xb.w : 0.0f;
            *(float4*)(orow + 8 * c)     = oa;
            *(float4*)(orow + 8 * c + 4) = ob;
        }
    } else {
        // split ties by lowest column index: lane-ordered exclusive prefix of
        // per-lane equal counts (lane owns contiguous cols -> lane order = col order)
        unsigned eq = 0;
#pragma unroll
        for (int j = 0; j < LPT; ++j) eq += (sc[j] == T) ? 1u : 0u;
        unsigned S = eq;
#pragma unroll
        for (int off = 1; off < 64; off <<= 1) {
            unsigned u = __shfl_up(S, off);
            if (lane >= off) S += u;
        }
        unsigned ebase = S - eq;            // #equals in lower columns
#pragma unroll
        for (int c = 0; c < 4; ++c) {
            float4 xa = *(const float4*)(xr + 8 * c);
            float4 xb = *(const float4*)(xr + 8 * c + 4);
            float xs[8] = {xa.x, xa.y, xa.z, xa.w, xb.x, xb.y, xb.z, xb.w};
            float o[8];
#pragma unroll
            for (int j = 0; j < 8; ++j) {
                unsigned s = sc[8 * c + j];
                bool pick = s > T;
                if (s == T) { pick = (ebase < kk); ebase += 1; }
                o[j] = pick ? xs[j] : 0.0f;
            }
            *(float4*)(orow + 8 * c)     = make_float4(o[0], o[1], o[2], o[3]);
            *(float4*)(orow + 8 * c + 4) = make_float4(o[4], o[5], o[6], o[7]);
        }
    }
}

extern "C" void kernel_launch(void* const* d_in, const int* in_sizes, int n_in,
                              void* d_out, int out_size, void* d_ws, size_t ws_size,
                              hipStream_t stream)
{
    const float* x   = (const float*)d_in[0];
    const float* imp = (const float*)d_in[1];
    float* out       = (float*)d_out;

    const int rows = in_sizes[0] / COLS;     // 32768
    CompetitiveSelection_topk_kernel<<<dim3(rows / RPB), dim3(TPB), 0, stream>>>(x, imp, out);
}

// Round 5
// 155.967 us; speedup vs baseline: 2.1570x; 2.1570x over previous
//
#include <hip/hip_runtime.h>

#define COLS 2048
#define KSEL 256
#define TPB  256
#define RPB  4            // rows per block = waves per block (no barriers!)
#define RSTRIDE 1072      // LDS words per row region
// Per-row region (word offsets):
//   [0..1055]   P1 hist, 4 replicas x 264 (odd stride); replica0[0..255] = bins
//               for later passes
//   [264..519]  compact list buffer (cap 256)   (inside replica1, reused)
//   [528..591]  recompact buffer (cap 64)       (inside replica2, reused)
#define BUFOFF 264
#define R2OFF  528

__device__ __forceinline__ unsigned rfl(unsigned v) {
    return (unsigned)__builtin_amdgcn_readfirstlane((int)v);
}

// One WAVE per row, zero __syncthreads (wave-private LDS regions).
// COALESCED chunk layout: lane l owns cols 4l + 256c + j (c=0..7, j=0..3) ->
// every float4 global access is a contiguous 1KB wave transaction.
// Exact top-K radix select on score bits (non-negative -> uint monotone).
// Tie handling matches jax.lax.top_k (lower column index first).
__global__ __launch_bounds__(TPB, 4)
void CompetitiveSelection_topk_kernel(const float* __restrict__ x,
                                      const float* __restrict__ imp,
                                      float* __restrict__ out)
{
    __shared__ __align__(16) unsigned int lds[RPB * RSTRIDE];
    const int lane = threadIdx.x & 63;
    const int wid  = threadIdx.x >> 6;
    unsigned int* reg = lds + wid * RSTRIDE;
    const int row = blockIdx.x * RPB + wid;
    const long gb = (long)row * COLS + 4 * lane;
    const float* xr = x + gb;
    const float* ir = imp + 4 * lane;

    // ---- load x (kept in regs; NO re-read later) + scores ----
    float    xs[32];
    unsigned sc[32];
#pragma unroll
    for (int c = 0; c < 8; ++c) {
        float4 xa = *(const float4*)(xr + 256 * c);
        float4 ia = *(const float4*)(ir + 256 * c);
        *(float4*)&xs[4 * c] = xa;
        sc[4*c+0] = __float_as_uint(fabsf(xa.x) * fabsf(ia.x));
        sc[4*c+1] = __float_as_uint(fabsf(xa.y) * fabsf(ia.y));
        sc[4*c+2] = __float_as_uint(fabsf(xa.z) * fabsf(ia.z));
        sc[4*c+3] = __float_as_uint(fabsf(xa.w) * fabsf(ia.w));
    }

    unsigned T = 0, kk = KSEL, na = 0, hm = 0xFF800000u;
    int nb = 23;

    // in-wave: suffix-scan 256 bin counts (4/lane), find crossing bin, broadcast
    auto scanfind = [&](const unsigned* c4, unsigned curT, int shift, unsigned curkk) {
        unsigned tot = c4[0] + c4[1] + c4[2] + c4[3];
        unsigned S = tot;
#pragma unroll
        for (int off = 1; off < 64; off <<= 1) {
            unsigned u = __shfl_down(S, off);
            if (lane + off < 64) S += u;
        }
        unsigned above = S - tot;          // count in bins > 4*lane+3
        int cc = -1; unsigned cab = 0, cnb = 0;
#pragma unroll
        for (int b = 3; b >= 0; --b) {
            if (cc < 0 && above < curkk && above + c4[b] >= curkk) {
                cc = 4 * lane + b; cab = above; cnb = c4[b];
            }
            above += c4[b];
        }
        unsigned long long m = __ballot(cc >= 0);   // exactly one lane
        int src = __ffsll(m) - 1;
        T  = rfl(curT | ((unsigned)__shfl(cc, src) << shift));
        kk = rfl(curkk - (unsigned)__shfl((int)cab, src));
        na = rfl((unsigned)__shfl((int)cnb, src));
    };

    // =================== P1: bits[30:23], 4 salted replicas ===================
    {
        const uint4 z4 = make_uint4(0, 0, 0, 0);
#pragma unroll
        for (int k = 0; k < 4; ++k) *(uint4*)&reg[256 * k + 4 * lane] = z4;
        if (lane < 8) *(uint4*)&reg[1024 + 4 * lane] = z4;

        const unsigned rb = 264u * (lane & 3u);
#pragma unroll
        for (int j = 0; j < 32; ++j)
            atomicAdd(&reg[rb + (sc[j] >> 23)], 1u);

        uint4 a = *(const uint4*)&reg[0 * 264 + 4 * lane];
        uint4 b = *(const uint4*)&reg[1 * 264 + 4 * lane];
        uint4 c = *(const uint4*)&reg[2 * 264 + 4 * lane];
        uint4 d = *(const uint4*)&reg[3 * 264 + 4 * lane];
        unsigned c4[4] = {a.x + b.x + c.x + d.x, a.y + b.y + c.y + d.y,
                          a.z + b.z + c.z + d.z, a.w + b.w + c.w + d.w};
        scanfind(c4, 0u, 23, KSEL);
    }

    unsigned nlist = 0; bool haveList = false;

    // compact active values (<=256) into BUF; list order is irrelevant
    auto compact = [&]() {
        unsigned cnt = 0;
#pragma unroll
        for (int j = 0; j < 32; ++j) cnt += ((sc[j] & hm) == T) ? 1u : 0u;
        unsigned S = cnt;
#pragma unroll
        for (int off = 1; off < 64; off <<= 1) {
            unsigned u = __shfl_up(S, off);
            if (lane >= off) S += u;
        }
        unsigned p = S - cnt;              // exclusive prefix = my write base
#pragma unroll
        for (int j = 0; j < 32; ++j)
            if ((sc[j] & hm) == T) reg[BUFOFF + p++] = sc[j];
        nlist = rfl((unsigned)__shfl((int)S, 63));
        haveList = true;
    };

    // histogram pass over compacted list, digit bits[s+7:s], single copy
    auto listpass = [&](int s) {
        *(uint4*)&reg[4 * lane] = make_uint4(0, 0, 0, 0);
        for (unsigned idx = (unsigned)lane; idx < nlist; idx += 64u) {
            unsigned v = reg[BUFOFF + idx];
            if ((v & hm) == T) atomicAdd(&reg[(v >> s) & 255u], 1u);
        }
        uint4 h = *(const uint4*)&reg[4 * lane];
        unsigned c4[4] = {h.x, h.y, h.z, h.w};
        scanfind(c4, T, s, kk);
    };

    // fallback: histogram over all 32 regs (fat boundary-bin rows)
    auto fullpass = [&](int s) {
        *(uint4*)&reg[4 * lane] = make_uint4(0, 0, 0, 0);
#pragma unroll
        for (int j = 0; j < 32; ++j)
            if ((sc[j] & hm) == T) atomicAdd(&reg[(sc[j] >> s) & 255u], 1u);
        uint4 h = *(const uint4*)&reg[4 * lane];
        unsigned c4[4] = {h.x, h.y, h.z, h.w};
        scanfind(c4, T, s, kk);
    };

    while (na > 64u && nb > 0) {
        int s = (nb == 23) ? 15 : (nb == 15) ? 7 : 0;
        if (!haveList && na <= 256u) compact();
        if (haveList) listpass(s); else fullpass(s);
        nb = s; hm |= (0xFFu << s);
    }

    unsigned ne;
    if (na > 64u) {
        ne = na;                            // nb==0: T exact, na == #equals
    } else {
        if (!haveList) compact();           // na <= 64 <= 256
        if (nb > 0) {
            // recompact currently-active list entries into R2 (<=64)
            unsigned cnt2 = 0;
            for (unsigned idx = (unsigned)lane; idx < nlist; idx += 64u) {
                unsigned v = reg[BUFOFF + idx];
                cnt2 += ((v & hm) == T) ? 1u : 0u;
            }
            unsigned S2 = cnt2;
#pragma unroll
            for (int off = 1; off < 64; off <<= 1) {
                unsigned u = __shfl_up(S2, off);
                if (lane >= off) S2 += u;
            }
            unsigned p2 = S2 - cnt2;
            for (unsigned idx = (unsigned)lane; idx < nlist; idx += 64u) {
                unsigned v = reg[BUFOFF + idx];
                if ((v & hm) == T) reg[R2OFF + p2++] = v;
            }
            unsigned na2 = rfl((unsigned)__shfl((int)S2, 63));   // == na
            // wave ballot-radix over remaining nb bits (exact)
            unsigned v = reg[R2OFF + lane];
            unsigned long long M = __ballot((unsigned)lane < na2);
            unsigned tl = 0, k2 = kk;
            for (int b = nb - 1; b >= 0; --b) {
                unsigned long long ones = __ballot((v >> b) & 1u) & M;
                unsigned c1 = (unsigned)__popcll(ones);
                if (c1 >= k2) { M = ones; tl |= (1u << b); }
                else          { M &= ~ones; k2 -= c1; }
            }
            T = rfl(T | tl); kk = rfl(k2); ne = rfl((unsigned)__popcll(M));
        } else {
            ne = na;
        }
    }

    // ---- epilogue: apply exact mask from registers (coalesced stores) ----
    float* orow = out + gb;
    if (ne == kk) {                         // no boundary-tie split (common)
#pragma unroll
        for (int c = 0; c < 8; ++c) {
            float4 o;
            o.x = (sc[4*c+0] >= T) ? xs[4*c+0] : 0.0f;
            o.y = (sc[4*c+1] >= T) ? xs[4*c+1] : 0.0f;
            o.z = (sc[4*c+2] >= T) ? xs[4*c+2] : 0.0f;
            o.w = (sc[4*c+3] >= T) ? xs[4*c+3] : 0.0f;
            *(float4*)(orow + 256 * c) = o;
        }
    } else {
        // split ties by lowest column: col = 256c + 4*lane + j, ordered (c,lane,j)
        unsigned tot = 0;
#pragma unroll
        for (int c = 0; c < 8; ++c) {
            unsigned eqc = 0;
#pragma unroll
            for (int j = 0; j < 4; ++j) eqc += (sc[4*c+j] == T) ? 1u : 0u;
            unsigned S = eqc;
#pragma unroll
            for (int off = 1; off < 64; off <<= 1) {
                unsigned u = __shfl_up(S, off);
                if (lane >= off) S += u;
            }
            unsigned ebase = tot + S - eqc;  // equals in lower columns
            float o[4];
#pragma unroll
            for (int j = 0; j < 4; ++j) {
                unsigned s = sc[4*c+j];
                bool pick = s > T;
                if (s == T) { pick = (ebase < kk); ebase += 1; }
                o[j] = pick ? xs[4*c+j] : 0.0f;
            }
            *(float4*)(orow + 256 * c) = make_float4(o[0], o[1], o[2], o[3]);
            tot += rfl((unsigned)__shfl((int)S, 63));
        }
    }
}

extern "C" void kernel_launch(void* const* d_in, const int* in_sizes, int n_in,
                              void* d_out, int out_size, void* d_ws, size_t ws_size,
                              hipStream_t stream)
{
    const float* x   = (const float*)d_in[0];
    const float* imp = (const float*)d_in[1];
    float* out       = (float*)d_out;

    const int rows = in_sizes[0] / COLS;     // 32768
    CompetitiveSelection_topk_kernel<<<dim3(rows / RPB), dim3(TPB), 0, stream>>>(x, imp, out);
}

// Round 6
// 140.185 us; speedup vs baseline: 2.3998x; 1.1126x over previous
//
#include <hip/hip_runtime.h>

#define COLS 2048
#define KSEL 256
#define TPB  256
#define RPB  4            // rows per block = waves per block (no barriers)
#define RSTRIDE 1072      // LDS words per row region
// Per-row region (word offsets):
//   [0..1055]   P1 hist, 4 replicas x 264 (odd stride); replica0[0..255] = bins
//               for later passes
//   [264..519]  compact list buffer (cap 256)  (inside replica1, reused)
//   [528..591]  recompact buffer (cap 64)      (inside replica2, reused)
//   [1056]      compact append counter, [1057] recompact append counter
#define BUFOFF 264
#define R2OFF  528
#define CNT0   1056
#define CNT1   1057

__device__ __forceinline__ unsigned rfl(unsigned v) {
    return (unsigned)__builtin_amdgcn_readfirstlane((int)v);
}

// One WAVE per row, zero __syncthreads (wave-private LDS regions).
// Coalesced chunk layout: lane l owns cols 4l + 256c + j (c=0..7, j=0..3).
// Scores (|x|*|imp|, non-negative -> uint monotone) are NEVER stored as a
// persistent array: computed on the fly in P1 and recomputed (bit-identical
// single multiply) in compact/epilogue sweeps. Keeps VGPR <= 64, no scratch.
// Tie handling matches jax.lax.top_k (lower column index first).
__global__ __launch_bounds__(TPB, 4)
void CompetitiveSelection_topk_kernel(const float* __restrict__ x,
                                      const float* __restrict__ imp,
                                      float* __restrict__ out)
{
    __shared__ __align__(16) unsigned int lds[RPB * RSTRIDE];
    const int lane = threadIdx.x & 63;
    const int wid  = threadIdx.x >> 6;
    unsigned int* reg = lds + wid * RSTRIDE;
    const int row = blockIdx.x * RPB + wid;
    const long gb = (long)row * COLS + 4 * lane;
    const float* xr = x + gb;
    const float* ir = imp + 4 * lane;

    unsigned T = 0, kk = KSEL, na = 0, hm = 0xFF800000u;
    int nb = 23;

    // in-wave: suffix-scan 256 bin counts (4/lane), find crossing bin, broadcast
    auto scanfind = [&](const unsigned* c4, unsigned curT, int shift, unsigned curkk) {
        unsigned tot = c4[0] + c4[1] + c4[2] + c4[3];
        unsigned S = tot;
#pragma unroll
        for (int off = 1; off < 64; off <<= 1) {
            unsigned u = __shfl_down(S, off);
            if (lane + off < 64) S += u;
        }
        unsigned above = S - tot;          // count in bins > 4*lane+3
        int cc = -1; unsigned cab = 0, cnb = 0;
#pragma unroll
        for (int b = 3; b >= 0; --b) {
            if (cc < 0 && above < curkk && above + c4[b] >= curkk) {
                cc = 4 * lane + b; cab = above; cnb = c4[b];
            }
            above += c4[b];
        }
        unsigned long long m = __ballot(cc >= 0);   // exactly one lane
        int src = __ffsll(m) - 1;
        T  = rfl(curT | ((unsigned)__shfl(cc, src) << shift));
        kk = rfl(curkk - (unsigned)__shfl((int)cab, src));
        na = rfl((unsigned)__shfl((int)cnb, src));
    };

    // ---- clear P1 hist (+ append counters) ----
    {
        const uint4 z4 = make_uint4(0, 0, 0, 0);
#pragma unroll
        for (int k = 0; k < 4; ++k) *(uint4*)&reg[256 * k + 4 * lane] = z4;
        if (lane < 9) *(uint4*)&reg[1024 + 4 * lane] = z4;   // 1024..1059
    }

    // ---- fused load + score + P1 atomics (bits[30:23], 4 salted replicas) ----
    float xs[32];
    {
        const unsigned rb = 264u * (lane & 3u);
#pragma unroll
        for (int c = 0; c < 8; ++c) {
            float4 xa = *(const float4*)(xr + 256 * c);
            float4 ia = *(const float4*)(ir + 256 * c);
            *(float4*)&xs[4 * c] = xa;
            unsigned d0 = __float_as_uint(fabsf(xa.x) * fabsf(ia.x)) >> 23;
            unsigned d1 = __float_as_uint(fabsf(xa.y) * fabsf(ia.y)) >> 23;
            unsigned d2 = __float_as_uint(fabsf(xa.z) * fabsf(ia.z)) >> 23;
            unsigned d3 = __float_as_uint(fabsf(xa.w) * fabsf(ia.w)) >> 23;
            // in-thread merge of equal digits cuts hot-bin atomic serialization
            atomicAdd(&reg[rb + d0], 1u + (d1 == d0) + (d2 == d0) + (d3 == d0));
            if (d1 != d0)                         atomicAdd(&reg[rb + d1], 1u + (d2 == d1) + (d3 == d1));
            if (d2 != d0 && d2 != d1)             atomicAdd(&reg[rb + d2], 1u + (d3 == d2));
            if (d3 != d0 && d3 != d1 && d3 != d2) atomicAdd(&reg[rb + d3], 1u);
        }
        uint4 a = *(const uint4*)&reg[0 * 264 + 4 * lane];
        uint4 b = *(const uint4*)&reg[1 * 264 + 4 * lane];
        uint4 c = *(const uint4*)&reg[2 * 264 + 4 * lane];
        uint4 d = *(const uint4*)&reg[3 * 264 + 4 * lane];
        unsigned c4[4] = {a.x + b.x + c.x + d.x, a.y + b.y + c.y + d.y,
                          a.z + b.z + c.z + d.z, a.w + b.w + c.w + d.w};
        scanfind(c4, 0u, 23, KSEL);
    }

    unsigned nlist = 0; bool haveList = false;

    // compact active scores (<=256) into BUF via atomic append (order irrelevant)
    auto compact = [&]() {
#pragma unroll
        for (int c = 0; c < 8; ++c) {
            float4 ia = *(const float4*)(ir + 256 * c);
            unsigned s0 = __float_as_uint(fabsf(xs[4*c+0]) * fabsf(ia.x));
            unsigned s1 = __float_as_uint(fabsf(xs[4*c+1]) * fabsf(ia.y));
            unsigned s2 = __float_as_uint(fabsf(xs[4*c+2]) * fabsf(ia.z));
            unsigned s3 = __float_as_uint(fabsf(xs[4*c+3]) * fabsf(ia.w));
            if ((s0 & hm) == T) { unsigned p = atomicAdd(&reg[CNT0], 1u); reg[BUFOFF + p] = s0; }
            if ((s1 & hm) == T) { unsigned p = atomicAdd(&reg[CNT0], 1u); reg[BUFOFF + p] = s1; }
            if ((s2 & hm) == T) { unsigned p = atomicAdd(&reg[CNT0], 1u); reg[BUFOFF + p] = s2; }
            if ((s3 & hm) == T) { unsigned p = atomicAdd(&reg[CNT0], 1u); reg[BUFOFF + p] = s3; }
        }
        nlist = rfl(reg[CNT0]);            // all prior LDS ops in-wave ordered
        haveList = true;
    };

    // histogram pass over compacted list, digit bits[s+7:s], single copy
    auto listpass = [&](int s) {
        *(uint4*)&reg[4 * lane] = make_uint4(0, 0, 0, 0);
        for (unsigned idx = (unsigned)lane; idx < nlist; idx += 64u) {
            unsigned v = reg[BUFOFF + idx];
            if ((v & hm) == T) atomicAdd(&reg[(v >> s) & 255u], 1u);
        }
        uint4 h = *(const uint4*)&reg[4 * lane];
        unsigned c4[4] = {h.x, h.y, h.z, h.w};
        scanfind(c4, T, s, kk);
    };

    // fallback: histogram over all 32 elems, scores recomputed (rare fat-bin rows)
    auto fullpass = [&](int s) {
        *(uint4*)&reg[4 * lane] = make_uint4(0, 0, 0, 0);
#pragma unroll
        for (int c = 0; c < 8; ++c) {
            float4 ia = *(const float4*)(ir + 256 * c);
            unsigned sv[4];
            sv[0] = __float_as_uint(fabsf(xs[4*c+0]) * fabsf(ia.x));
            sv[1] = __float_as_uint(fabsf(xs[4*c+1]) * fabsf(ia.y));
            sv[2] = __float_as_uint(fabsf(xs[4*c+2]) * fabsf(ia.z));
            sv[3] = __float_as_uint(fabsf(xs[4*c+3]) * fabsf(ia.w));
#pragma unroll
            for (int j = 0; j < 4; ++j)
                if ((sv[j] & hm) == T) atomicAdd(&reg[(sv[j] >> s) & 255u], 1u);
        }
        uint4 h = *(const uint4*)&reg[4 * lane];
        unsigned c4[4] = {h.x, h.y, h.z, h.w};
        scanfind(c4, T, s, kk);
    };

    while (na > 64u && nb > 0) {
        int s = (nb == 23) ? 15 : (nb == 15) ? 7 : 0;
        if (!haveList && na <= 256u) compact();
        if (haveList) listpass(s); else fullpass(s);
        nb = s; hm |= (0xFFu << s);
    }

    unsigned ne;
    if (na > 64u) {
        ne = na;                            // nb==0: T exact, na == #equals
    } else {
        if (!haveList) compact();           // na <= 64 <= 256
        if (nb > 0) {
            // recompact currently-active list entries into R2 (<=64)
            for (unsigned idx = (unsigned)lane; idx < nlist; idx += 64u) {
                unsigned v = reg[BUFOFF + idx];
                if ((v & hm) == T) { unsigned p = atomicAdd(&reg[CNT1], 1u); reg[R2OFF + p] = v; }
            }
            // wave ballot-radix over remaining nb bits (exact)
            unsigned v = reg[R2OFF + lane];
            unsigned long long M = __ballot((unsigned)lane < na);
            unsigned tl = 0, k2 = kk;
            for (int b = nb - 1; b >= 0; --b) {
                unsigned long long ones = __ballot((v >> b) & 1u) & M;
                unsigned c1 = (unsigned)__popcll(ones);
                if (c1 >= k2) { M = ones; tl |= (1u << b); }
                else          { M &= ~ones; k2 -= c1; }
            }
            T = rfl(T | tl); kk = rfl(k2); ne = rfl((unsigned)__popcll(M));
        } else {
            ne = na;
        }
    }

    // ---- epilogue: recompute scores, apply exact mask (coalesced stores) ----
    float* orow = out + gb;
    if (ne == kk) {                         // no boundary-tie split (common)
#pragma unroll
        for (int c = 0; c < 8; ++c) {
            float4 ia = *(const float4*)(ir + 256 * c);
            float4 o;
            o.x = (__float_as_uint(fabsf(xs[4*c+0]) * fabsf(ia.x)) >= T) ? xs[4*c+0] : 0.0f;
            o.y = (__float_as_uint(fabsf(xs[4*c+1]) * fabsf(ia.y)) >= T) ? xs[4*c+1] : 0.0f;
            o.z = (__float_as_uint(fabsf(xs[4*c+2]) * fabsf(ia.z)) >= T) ? xs[4*c+2] : 0.0f;
            o.w = (__float_as_uint(fabsf(xs[4*c+3]) * fabsf(ia.w)) >= T) ? xs[4*c+3] : 0.0f;
            *(float4*)(orow + 256 * c) = o;
        }
    } else {
        // split ties by lowest column: col = 256c + 4*lane + j, ordered (c,lane,j)
        unsigned tot = 0;
#pragma unroll
        for (int c = 0; c < 8; ++c) {
            float4 ia = *(const float4*)(ir + 256 * c);
            unsigned sv[4];
            sv[0] = __float_as_uint(fabsf(xs[4*c+0]) * fabsf(ia.x));
            sv[1] = __float_as_uint(fabsf(xs[4*c+1]) * fabsf(ia.y));
            sv[2] = __float_as_uint(fabsf(xs[4*c+2]) * fabsf(ia.z));
            sv[3] = __float_as_uint(fabsf(xs[4*c+3]) * fabsf(ia.w));
            unsigned eqc = (sv[0] == T) + (sv[1] == T) + (sv[2] == T) + (sv[3] == T);
            unsigned S = eqc;
#pragma unroll
            for (int off = 1; off < 64; off <<= 1) {
                unsigned u = __shfl_up(S, off);
                if (lane >= off) S += u;
            }
            unsigned ebase = tot + S - eqc;  // equals in lower columns
            float o[4];
#pragma unroll
            for (int j = 0; j < 4; ++j) {
                bool pick = sv[j] > T;
                if (sv[j] == T) { pick = (ebase < kk); ebase += 1; }
                o[j] = pick ? xs[4*c+j] : 0.0f;
            }
            *(float4*)(orow + 256 * c) = make_float4(o[0], o[1], o[2], o[3]);
            tot += rfl((unsigned)__shfl((int)S, 63));
        }
    }
}

extern "C" void kernel_launch(void* const* d_in, const int* in_sizes, int n_in,
                              void* d_out, int out_size, void* d_ws, size_t ws_size,
                              hipStream_t stream)
{
    const float* x   = (const float*)d_in[0];
    const float* imp = (const float*)d_in[1];
    float* out       = (float*)d_out;

    const int rows = in_sizes[0] / COLS;     // 32768
    CompetitiveSelection_topk_kernel<<<dim3(rows / RPB), dim3(TPB), 0, stream>>>(x, imp, out);
}

// Round 7
// 132.060 us; speedup vs baseline: 2.5475x; 1.0615x over previous
//
#include <hip/hip_runtime.h>

#define COLS 2048
#define KSEL 256
#define TPB  256
#define RPB  4            // rows per block = waves per block (no barriers)
#define RSTRIDE 1296      // LDS words per row region
// Per-row region (word offsets):
//   P1: 1024-bin hist, bin b at addr b + 4*(b>>4)  -> [0..1275]
//   after P1 dead; reused: [0..255] fallback 256-bin hist,
//                          [256..511] compact list BUF (cap 256),
//                          [512..575] final list R2 (cap 64)
#define BUFOFF 256
#define R2OFF  512

__device__ __forceinline__ unsigned rfl(unsigned v) {
    return (unsigned)__builtin_amdgcn_readfirstlane((int)v);
}
__device__ __forceinline__ unsigned mbcnt64(unsigned long long m) {
    unsigned c = __builtin_amdgcn_mbcnt_lo((unsigned)m, 0u);
    return __builtin_amdgcn_mbcnt_hi((unsigned)(m >> 32), c);
}
// score = |x*imp| bits; identical to |x|*|imp| (sign only affects sign bit)
__device__ __forceinline__ unsigned scoreOf(float xv, float iv) {
    return __float_as_uint(xv * iv) & 0x7FFFFFFFu;
}

// One WAVE per row, zero __syncthreads (wave-private LDS regions).
// Coalesced chunk layout: lane l owns cols 4l + 256c + j (c=0..7, j=0..3).
// P1: 1024-bin radix pass on bits[30:21] (atomics ~conflict-free).
// Then wave ballot-radix on the <=64 survivors (common), with exact
// list/full fallback passes for fat boundary bins.
// Tie handling matches jax.lax.top_k (lower column index first).
__global__ __launch_bounds__(TPB, 4)
void CompetitiveSelection_topk_kernel(const float* __restrict__ x,
                                      const float* __restrict__ imp,
                                      float* __restrict__ out)
{
    __shared__ __align__(16) unsigned int lds[RPB * RSTRIDE];
    const int lane = threadIdx.x & 63;
    const int wid  = threadIdx.x >> 6;
    unsigned int* reg = lds + wid * RSTRIDE;
    const int row = blockIdx.x * RPB + wid;
    const long gb = (long)row * COLS + 4 * lane;
    const float* xr = x + gb;
    const float* ir = imp + 4 * lane;

    unsigned T = 0, kk = KSEL, na = 0;
    unsigned hm = 0xFFE00000u;             // determined-bit mask after P1
    int nb = 21;                           // undetermined low bits

    // broadcast helper for scan results
    auto bcast = [&](int cc, unsigned cab, unsigned cnb, unsigned curT,
                     int shift, unsigned curkk) {
        unsigned long long m = __ballot(cc >= 0);   // exactly one lane
        int src = __ffsll(m) - 1;
        T  = rfl(curT | ((unsigned)__shfl(cc, src) << shift));
        kk = rfl(curkk - (unsigned)__shfl((int)cab, src));
        na = rfl((unsigned)__shfl((int)cnb, src));
    };

    // ---- clear P1 hist (1280 padded words, 5 x uint4 per lane) ----
    {
        const uint4 z4 = make_uint4(0, 0, 0, 0);
#pragma unroll
        for (int k = 0; k < 5; ++k) *(uint4*)&reg[20 * lane + 4 * k] = z4;
    }

    // ---- fused load + score + P1 atomics (bits[30:21], 1024 bins) ----
    float xs[32];
    {
#pragma unroll
        for (int c = 0; c < 8; ++c) {
            float4 xa = *(const float4*)(xr + 256 * c);
            float4 ia = *(const float4*)(ir + 256 * c);
            *(float4*)&xs[4 * c] = xa;
            unsigned d0 = scoreOf(xa.x, ia.x) >> 21;
            unsigned d1 = scoreOf(xa.y, ia.y) >> 21;
            unsigned d2 = scoreOf(xa.z, ia.z) >> 21;
            unsigned d3 = scoreOf(xa.w, ia.w) >> 21;
            atomicAdd(&reg[d0 + 4 * (d0 >> 4)], 1u);
            atomicAdd(&reg[d1 + 4 * (d1 >> 4)], 1u);
            atomicAdd(&reg[d2 + 4 * (d2 >> 4)], 1u);
            atomicAdd(&reg[d3 + 4 * (d3 >> 4)], 1u);
        }
        // lane owns bins [16*lane .. 16*lane+15] at addr 20*lane + m
        uint4 h0 = *(const uint4*)&reg[20 * lane + 0];
        uint4 h1 = *(const uint4*)&reg[20 * lane + 4];
        uint4 h2 = *(const uint4*)&reg[20 * lane + 8];
        uint4 h3 = *(const uint4*)&reg[20 * lane + 12];
        unsigned cnt[16] = {h0.x, h0.y, h0.z, h0.w, h1.x, h1.y, h1.z, h1.w,
                            h2.x, h2.y, h2.z, h2.w, h3.x, h3.y, h3.z, h3.w};
        unsigned tot = 0;
#pragma unroll
        for (int m = 0; m < 16; ++m) tot += cnt[m];
        unsigned S = tot;                  // suffix sum over lanes >= lane
#pragma unroll
        for (int off = 1; off < 64; off <<= 1) {
            unsigned u = __shfl_down(S, off);
            if (lane + off < 64) S += u;
        }
        unsigned above = S - tot;          // count in bins > 16*lane+15
        int cc = -1; unsigned cab = 0, cnb = 0;
#pragma unroll
        for (int b = 15; b >= 0; --b) {
            if (cc < 0 && above < KSEL && above + cnt[b] >= KSEL) {
                cc = 16 * lane + b; cab = above; cnb = cnt[b];
            }
            above += cnt[b];
        }
        bcast(cc, cab, cnb, 0u, 21, KSEL);
    }

    unsigned nlist = 0; bool haveList = false;

    // ballot-prefix compaction of active scores (recomputed) into reg[dstOff..]
    auto compactTo = [&](unsigned dstOff) -> unsigned {
        unsigned run = 0;
#pragma unroll
        for (int c = 0; c < 8; ++c) {
            float4 ia = *(const float4*)(ir + 256 * c);
            unsigned sv[4];
            sv[0] = scoreOf(xs[4*c+0], ia.x);
            sv[1] = scoreOf(xs[4*c+1], ia.y);
            sv[2] = scoreOf(xs[4*c+2], ia.z);
            sv[3] = scoreOf(xs[4*c+3], ia.w);
#pragma unroll
            for (int j = 0; j < 4; ++j) {
                bool act = (sv[j] & hm) == T;
                unsigned long long m = __ballot(act);
                if (act) reg[dstOff + run + mbcnt64(m)] = sv[j];
                run += (unsigned)__popcll(m);
            }
        }
        return run;                        // wave-uniform
    };

    // 256-bin scanfind over reg[0..255] (4 bins/lane)
    auto scanfind256 = [&](int s) {
        uint4 h = *(const uint4*)&reg[4 * lane];
        unsigned cnt[4] = {h.x, h.y, h.z, h.w};
        unsigned tot = cnt[0] + cnt[1] + cnt[2] + cnt[3];
        unsigned S = tot;
#pragma unroll
        for (int off = 1; off < 64; off <<= 1) {
            unsigned u = __shfl_down(S, off);
            if (lane + off < 64) S += u;
        }
        unsigned above = S - tot;
        int cc = -1; unsigned cab = 0, cnb = 0;
#pragma unroll
        for (int b = 3; b >= 0; --b) {
            if (cc < 0 && above < kk && above + cnt[b] >= kk) {
                cc = 4 * lane + b; cab = above; cnb = cnt[b];
            }
            above += cnt[b];
        }
        bcast(cc, cab, cnb, T, s, kk);
    };

    // fallback refinement passes while the boundary bin stays fat
    while (na > 64u && nb > 0) {
        int s = (nb > 8) ? (nb - 8) : 0;
        if (!haveList && na <= 256u) { nlist = compactTo(BUFOFF); haveList = true; }
        *(uint4*)&reg[4 * lane] = make_uint4(0, 0, 0, 0);   // clear 256-bin hist
        if (haveList) {
            for (unsigned idx = (unsigned)lane; idx < nlist; idx += 64u) {
                unsigned v = reg[BUFOFF + idx];
                if ((v & hm) == T) atomicAdd(&reg[(v >> s) & 255u], 1u);
            }
        } else {
#pragma unroll
            for (int c = 0; c < 8; ++c) {
                float4 ia = *(const float4*)(ir + 256 * c);
                unsigned sv[4];
                sv[0] = scoreOf(xs[4*c+0], ia.x);
                sv[1] = scoreOf(xs[4*c+1], ia.y);
                sv[2] = scoreOf(xs[4*c+2], ia.z);
                sv[3] = scoreOf(xs[4*c+3], ia.w);
#pragma unroll
                for (int j = 0; j < 4; ++j)
                    if ((sv[j] & hm) == T) atomicAdd(&reg[(sv[j] >> s) & 255u], 1u);
            }
        }
        scanfind256(s);
        nb = s; hm |= (0xFFu << s);
    }

    unsigned ne;
    if (na > 64u) {
        ne = na;                           // nb==0: T exact, na == #equals
    } else if (nb > 0) {
        // gather <=64 survivors into R2
        if (haveList) {
            unsigned run2 = 0;
            const unsigned nit = (nlist + 63u) >> 6;
            for (unsigned k = 0; k < nit; ++k) {
                unsigned idx = (unsigned)lane + 64u * k;
                bool inb = idx < nlist;
                unsigned v = inb ? reg[BUFOFF + idx] : 0u;
                bool act = inb && ((v & hm) == T);
                unsigned long long m = __ballot(act);
                if (act) reg[R2OFF + run2 + mbcnt64(m)] = v;
                run2 += (unsigned)__popcll(m);
            }
        } else {
            compactTo(R2OFF);
        }
        // wave ballot-radix over remaining nb bits (exact)
        unsigned v = reg[R2OFF + lane];
        unsigned long long M = __ballot((unsigned)lane < na);
        unsigned tl = 0, k2 = kk;
        for (int b = nb - 1; b >= 0; --b) {
            unsigned long long ones = __ballot((v >> b) & 1u) & M;
            unsigned c1 = (unsigned)__popcll(ones);
            if (c1 >= k2) { M = ones; tl |= (1u << b); }
            else          { M &= ~ones; k2 -= c1; }
        }
        T = rfl(T | tl); kk = rfl(k2); ne = rfl((unsigned)__popcll(M));
    } else {
        ne = na;
    }

    // ---- epilogue: recompute scores, apply exact mask (coalesced stores) ----
    float* orow = out + gb;
    if (ne == kk) {                        // no boundary-tie split (common)
#pragma unroll
        for (int c = 0; c < 8; ++c) {
            float4 ia = *(const float4*)(ir + 256 * c);
            float4 o;
            o.x = (scoreOf(xs[4*c+0], ia.x) >= T) ? xs[4*c+0] : 0.0f;
            o.y = (scoreOf(xs[4*c+1], ia.y) >= T) ? xs[4*c+1] : 0.0f;
            o.z = (scoreOf(xs[4*c+2], ia.z) >= T) ? xs[4*c+2] : 0.0f;
            o.w = (scoreOf(xs[4*c+3], ia.w) >= T) ? xs[4*c+3] : 0.0f;
            *(float4*)(orow + 256 * c) = o;
        }
    } else {
        // split ties by lowest column: col = 256c + 4*lane + j, ordered (c,lane,j)
        unsigned tot = 0;
#pragma unroll
        for (int c = 0; c < 8; ++c) {
            float4 ia = *(const float4*)(ir + 256 * c);
            unsigned sv[4];
            sv[0] = scoreOf(xs[4*c+0], ia.x);
            sv[1] = scoreOf(xs[4*c+1], ia.y);
            sv[2] = scoreOf(xs[4*c+2], ia.z);
            sv[3] = scoreOf(xs[4*c+3], ia.w);
            unsigned eqc = (sv[0] == T) + (sv[1] == T) + (sv[2] == T) + (sv[3] == T);
            unsigned S = eqc;
#pragma unroll
            for (int off = 1; off < 64; off <<= 1) {
                unsigned u = __shfl_up(S, off);
                if (lane >= off) S += u;
            }
            unsigned ebase = tot + S - eqc;  // equals in lower columns
            float o[4];
#pragma unroll
            for (int j = 0; j < 4; ++j) {
                bool pick = sv[j] > T;
                if (sv[j] == T) { pick = (ebase < kk); ebase += 1; }
                o[j] = pick ? xs[4*c+j] : 0.0f;
            }
            *(float4*)(orow + 256 * c) = make_float4(o[0], o[1], o[2], o[3]);
            tot += rfl((unsigned)__shfl((int)S, 63));
        }
    }
}

extern "C" void kernel_launch(void* const* d_in, const int* in_sizes, int n_in,
                              void* d_out, int out_size, void* d_ws, size_t ws_size,
                              hipStream_t stream)
{
    const float* x   = (const float*)d_in[0];
    const float* imp = (const float*)d_in[1];
    float* out       = (float*)d_out;

    const int rows = in_sizes[0] / COLS;     // 32768
    CompetitiveSelection_topk_kernel<<<dim3(rows / RPB), dim3(TPB), 0, stream>>>(x, imp, out);
}